// Round 8
// baseline (1349.150 us; speedup 1.0000x reference)
//
#include <hip/hip_runtime.h>
#include <hip/hip_bf16.h>

// ConvTranspose4d: B=2, CIN=32, COUT=32, S=16^4, K=3^4, pad=0, stride=1
// y[b,co,o] = bias[co] + sum_{ci, k in [0,3)^4, 0<=o-k<16} x[b,ci,o-k] * w[ci,co,k]
// out spatial = 18^4.
//
// Block = (b,o0,o1), 648 blocks x 576 threads (9 full waves).
// Thread = (co-pair t&15, o2 = (t>>4)>>1, h = (t>>4)&1).
// Thread accumulates y[o3] for o3 = 8h + (m+k3), m in [0,8): i3 = 8h+m.
// Halves overlap at o3 in {8,9}; combined via LDS at epilogue.
//
// R7 counters: dur 564us, VALUBusy 57%, Occupancy 23% (~1 block/CU), conflicts 0.
// -> latency-bound from occupancy. CHUNK 4->2 (LDS 78->45KB, 3 blocks/CU) and
//    padded weight rows (12 floats, 16B-aligned -> b128 reads).

#define B_    2
#define CIN_  32
#define SD    16
#define OD    18
#define NTAP  81
#define CHUNK 2
#define THREADS 576

// LPT block ordering: decode r in [0,324) -> (o0,o1), heaviest class first.
// classes by n0*n1: 9 (196 pairs), 6 (56), 4 (4), 3 (56), 2 (8), 1 (4).
__device__ inline void decode_o01(int r, int& o0, int& o1) {
    if (r < 196) {                      // [2,15] x [2,15]
        o0 = 2 + r / 14; o1 = 2 + r % 14;
    } else if (r < 252) {               // cost 6
        int q = r - 196;
        if (q < 28) { o0 = 2 + (q >> 1); o1 = (q & 1) ? 16 : 1; }
        else { q -= 28;  o1 = 2 + (q >> 1); o0 = (q & 1) ? 16 : 1; }
    } else if (r < 256) {               // cost 4: {1,16}^2
        int q = r - 252;
        o0 = (q & 1) ? 16 : 1; o1 = (q >> 1) ? 16 : 1;
    } else if (r < 312) {               // cost 3
        int q = r - 256;
        if (q < 28) { o0 = 2 + (q >> 1); o1 = (q & 1) ? 17 : 0; }
        else { q -= 28;  o1 = 2 + (q >> 1); o0 = (q & 1) ? 17 : 0; }
    } else if (r < 320) {               // cost 2
        int q = r - 312;
        if (q < 4) { o0 = (q & 1) ? 16 : 1; o1 = (q >> 1) ? 17 : 0; }
        else { q -= 4; o0 = (q & 1) ? 17 : 0; o1 = (q >> 1) ? 16 : 1; }
    } else {                            // cost 1: {0,17}^2
        int q = r - 320;
        o0 = (q & 1) ? 17 : 0; o1 = (q >> 1) ? 17 : 0;
    }
}

__global__ __launch_bounds__(THREADS, 7)
void convt4d_kernel(const float* __restrict__ x,
                    const float* __restrict__ w,
                    const float* __restrict__ bias,
                    float* __restrict__ y) {
    const int bid = blockIdx.x;          // 0..647
    const int b   = bid & 1;
    int o0, o1;
    decode_o01(bid >> 1, o0, o1);

    const int t   = threadIdx.x;
    const int co  = t & 15;              // co-pair: owns co and co+16
    const int rr_ = t >> 4;              // 0..35
    const int h   = rr_ & 1;             // o3 half
    const int o2  = rr_ >> 1;            // 0..17
    const int i3b = h * 8;               // i3 base for this half

    // block-uniform valid k0/k1 tap ranges (i = o - k must be in [0,16))
    const int k0lo = max(0, o0 - (SD - 1)), k0hi = min(2, o0);
    const int k1lo = max(0, o1 - (SD - 1)), k1hi = min(2, o1);
    const int n0 = k0hi - k0lo + 1;      // 1..3
    const int n1 = k1hi - k1lo + 1;      // 1..3

    __shared__ float4 xs4[CHUNK][3][3][64];                 // 18.4 KB
    __shared__ __align__(16) float wsl[CHUNK * 9 * 32 * 12]; // 27.6 KB (rows padded 9->12)

    float a0[10], a1[10];
#pragma unroll
    for (int j = 0; j < 10; ++j) { a0[j] = 0.f; a1[j] = 0.f; }

    for (int cc = 0; cc < CIN_; cc += CHUNK) {
        // ---- stage x[b, cc..cc+CHUNK-1, i0(valid), i1(valid), :, :] into LDS ----
        {
            const int total4 = CHUNK * n0 * n1 * 64;     // <= 1152 float4
            for (int idx = t; idx < total4; idx += THREADS) {
                const int rw = idx >> 6, e = idx & 63;
                const int ci = rw / (n0 * n1);
                const int r2 = rw - ci * (n0 * n1);
                const int s0 = r2 / n1, s1 = r2 - s0 * n1;
                const int i0 = o0 - (k0lo + s0);
                const int i1 = o1 - (k1lo + s1);
                xs4[ci][s0][s1][e] = ((const float4*)(x +
                    ((((size_t)b * CIN_ + (cc + ci)) * SD + i0) * SD + i1) * (SD * SD)))[e];
            }
        }
        // ---- stage w chunk into padded LDS layout [ci][k01][co][12] ----
        // pad slots 9..11 never read. 5184 elems / 576 threads = 9 each.
        {
#pragma unroll
            for (int it = 0; it < CHUNK * 9 * 32 * 9 / THREADS; ++it) {
                const int idx = t + it * THREADS;
                const int q   = idx % 9;
                const int r   = idx / 9;
                const int cw  = r & 31;
                const int r2  = r >> 5;
                const int k01 = r2 % 9;
                const int ci  = r2 / 9;
                wsl[((ci * 9 + k01) * 32 + cw) * 12 + q] =
                    w[((size_t)(cc + ci) * 32 + cw) * NTAP + k01 * 9 + q];
            }
        }
        __syncthreads();

        // ---- compute ----
        for (int ci = 0; ci < CHUNK; ++ci) {
            for (int s0 = 0; s0 < n0; ++s0) {
                for (int s1 = 0; s1 < n1; ++s1) {
                    const int k01 = (k0lo + s0) * 3 + (k1lo + s1);
                    const float* wp0 = &wsl[((ci * 9 + k01) * 32 + co) * 12];
                    const float* wp1 = wp0 + 16 * 12;
                    const float4 wa0 = ((const float4*)wp0)[0];
                    const float4 wb0 = ((const float4*)wp0)[1];
                    const float  wc0 = wp0[8];
                    const float4 wa1 = ((const float4*)wp1)[0];
                    const float4 wb1 = ((const float4*)wp1)[1];
                    const float  wc1 = wp1[8];
                    const float wv0[9] = {wa0.x, wa0.y, wa0.z, wa0.w,
                                          wb0.x, wb0.y, wb0.z, wb0.w, wc0};
                    const float wv1[9] = {wa1.x, wa1.y, wa1.z, wa1.w,
                                          wb1.x, wb1.y, wb1.z, wb1.w, wc1};
                    const float* base = (const float*)xs4[ci][s0][s1];
#pragma unroll
                    for (int k2 = 0; k2 < 3; ++k2) {
                        const int i2 = o2 - k2;
                        if ((unsigned)i2 < (unsigned)SD) {
                            const float* xr = base + i2 * SD + i3b;
                            const float4 xa = ((const float4*)xr)[0];
                            const float4 xb = ((const float4*)xr)[1];
                            const float xv[8] = {xa.x, xa.y, xa.z, xa.w,
                                                 xb.x, xb.y, xb.z, xb.w};
#pragma unroll
                            for (int k3 = 0; k3 < 3; ++k3) {
                                const float c0 = wv0[k2 * 3 + k3];
                                const float c1 = wv1[k2 * 3 + k3];
#pragma unroll
                                for (int m = 0; m < 8; ++m) {
                                    a0[m + k3] += c0 * xv[m];   // o3 = 8h + m + k3
                                    a1[m + k3] += c1 * xv[m];
                                }
                            }
                        }
                    }
                }
            }
        }
        __syncthreads();
    }

    // ---- combine overlap (o3 = 8,9) via LDS, then write with bias ----
    float* bnd = (float*)xs4;            // xs dead after final barrier (needs 4.6KB < 18.4KB)
    const int slot = (o2 * 16 + co) * 4;
    if (h == 0) {
        bnd[slot + 0] = a0[8]; bnd[slot + 1] = a0[9];
        bnd[slot + 2] = a1[8]; bnd[slot + 3] = a1[9];
    }
    __syncthreads();

    const float bb0 = bias[co], bb1 = bias[co + 16];
    float* y0 = y + (((((size_t)b * 32 + co) * OD + o0) * OD + o1) * OD + o2) * OD;
    float* y1 = y0 + (size_t)16 * OD * OD * OD * OD;
    if (h == 0) {
        // o3 = 0..7
#pragma unroll
        for (int j = 0; j < 4; ++j) {
            ((float2*)y0)[j] = make_float2(a0[2 * j] + bb0, a0[2 * j + 1] + bb0);
            ((float2*)y1)[j] = make_float2(a1[2 * j] + bb1, a1[2 * j + 1] + bb1);
        }
    } else {
        // o3 = 8..17 ; slots 0,1 get the h=0 partial for o3=8,9
        a0[0] += bnd[slot + 0]; a0[1] += bnd[slot + 1];
        a1[0] += bnd[slot + 2]; a1[1] += bnd[slot + 3];
#pragma unroll
        for (int j = 0; j < 5; ++j) {
            ((float2*)(y0 + 8))[j] = make_float2(a0[2 * j] + bb0, a0[2 * j + 1] + bb0);
            ((float2*)(y1 + 8))[j] = make_float2(a1[2 * j] + bb1, a1[2 * j + 1] + bb1);
        }
    }
}

extern "C" void kernel_launch(void* const* d_in, const int* in_sizes, int n_in,
                              void* d_out, int out_size, void* d_ws, size_t ws_size,
                              hipStream_t stream) {
    const float* x    = (const float*)d_in[0];
    const float* w    = (const float*)d_in[1];
    const float* bias = (const float*)d_in[2];
    float* y = (float*)d_out;

    const int grid = B_ * OD * OD;   // 648 blocks: (b, o0, o1) LPT-ordered
    convt4d_kernel<<<grid, THREADS, 0, stream>>>(x, w, bias, y);
}

// Round 9
// 571.202 us; speedup vs baseline: 2.3619x; 2.3619x over previous
//
#include <hip/hip_runtime.h>
#include <hip/hip_bf16.h>

// ConvTranspose4d: B=2, CIN=32, COUT=32, S=16^4, K=3^4, pad=0, stride=1
// y[b,co,o] = bias[co] + sum_{ci, k in [0,3)^4, 0<=o-k<16} x[b,ci,o-k] * w[ci,co,k]
// out spatial = 18^4.
//
// Block = (b,o0,o1), 648 blocks x 576 threads (9 full waves).
// Thread = (co-pair t&15, o2 = (t>>4)>>1, h = (t>>4)&1).
// Thread accumulates y[o3] for o3 = 8h + (m+k3), m in [0,8): i3 = 8h+m.
// Halves overlap at o3 in {8,9}; combined via LDS at epilogue.
//
// R7 (CHUNK=4, lb(576,5)): 564us, VALUBusy 57%, Occ 23% (1 blk/CU), VGPR 48, confl 0.
// R8 (CHUNK=2, lb(576,7), padded w): 1349us FAILED — lb cap forced VGPR 48->36,
//   accumulator spill: WRITE 27->520MB, FETCH 40->531MB; padded-w added 2.8e7
//   conflict cycles. Lesson: never cap below the live set; keep layout with 0 confl.
// R9: r7 code, only CHUNK 4->2 (LDS 78->39KB -> 3 blk/CU, thread-limited 27 waves)
//   and lb back to (576,5).

#define B_    2
#define CIN_  32
#define SD    16
#define OD    18
#define NTAP  81
#define CHUNK 2
#define THREADS 576

// LPT block ordering: decode r in [0,324) -> (o0,o1), heaviest class first.
// classes by n0*n1: 9 (196 pairs), 6 (56), 4 (4), 3 (56), 2 (8), 1 (4).
__device__ inline void decode_o01(int r, int& o0, int& o1) {
    if (r < 196) {                      // [2,15] x [2,15]
        o0 = 2 + r / 14; o1 = 2 + r % 14;
    } else if (r < 252) {               // cost 6
        int q = r - 196;
        if (q < 28) { o0 = 2 + (q >> 1); o1 = (q & 1) ? 16 : 1; }
        else { q -= 28;  o1 = 2 + (q >> 1); o0 = (q & 1) ? 16 : 1; }
    } else if (r < 256) {               // cost 4: {1,16}^2
        int q = r - 252;
        o0 = (q & 1) ? 16 : 1; o1 = (q >> 1) ? 16 : 1;
    } else if (r < 312) {               // cost 3
        int q = r - 256;
        if (q < 28) { o0 = 2 + (q >> 1); o1 = (q & 1) ? 17 : 0; }
        else { q -= 28;  o1 = 2 + (q >> 1); o0 = (q & 1) ? 17 : 0; }
    } else if (r < 320) {               // cost 2
        int q = r - 312;
        if (q < 4) { o0 = (q & 1) ? 16 : 1; o1 = (q >> 1) ? 17 : 0; }
        else { q -= 4; o0 = (q & 1) ? 17 : 0; o1 = (q >> 1) ? 16 : 1; }
    } else {                            // cost 1: {0,17}^2
        int q = r - 320;
        o0 = (q & 1) ? 17 : 0; o1 = (q >> 1) ? 17 : 0;
    }
}

__global__ __launch_bounds__(THREADS, 5)
void convt4d_kernel(const float* __restrict__ x,
                    const float* __restrict__ w,
                    const float* __restrict__ bias,
                    float* __restrict__ y) {
    const int bid = blockIdx.x;          // 0..647
    const int b   = bid & 1;
    int o0, o1;
    decode_o01(bid >> 1, o0, o1);

    const int t   = threadIdx.x;
    const int co  = t & 15;              // co-pair: owns co and co+16
    const int rr_ = t >> 4;              // 0..35
    const int h   = rr_ & 1;             // o3 half
    const int o2  = rr_ >> 1;            // 0..17
    const int i3b = h * 8;               // i3 base for this half

    // block-uniform valid k0/k1 tap ranges (i = o - k must be in [0,16))
    const int k0lo = max(0, o0 - (SD - 1)), k0hi = min(2, o0);
    const int k1lo = max(0, o1 - (SD - 1)), k1hi = min(2, o1);
    const int n0 = k0hi - k0lo + 1;      // 1..3
    const int n1 = k1hi - k1lo + 1;      // 1..3

    __shared__ float4 xs4[CHUNK][3][3][64];        // 18.4 KB
    __shared__ float  wsl[CHUNK * 32 * NTAP];      // 20.7 KB

    float a0[10], a1[10];
#pragma unroll
    for (int j = 0; j < 10; ++j) { a0[j] = 0.f; a1[j] = 0.f; }

    for (int cc = 0; cc < CIN_; cc += CHUNK) {
        // ---- stage x[b, cc..cc+CHUNK-1, i0(valid), i1(valid), :, :] into LDS ----
        {
            const int total4 = CHUNK * n0 * n1 * 64;     // <= 1152 float4
            for (int idx = t; idx < total4; idx += THREADS) {
                const int rw = idx >> 6, e = idx & 63;
                const int ci = rw / (n0 * n1);
                const int r2 = rw - ci * (n0 * n1);
                const int s0 = r2 / n1, s1 = r2 - s0 * n1;
                const int i0 = o0 - (k0lo + s0);
                const int i1 = o1 - (k1lo + s1);
                xs4[ci][s0][s1][e] = ((const float4*)(x +
                    ((((size_t)b * CIN_ + (cc + ci)) * SD + i0) * SD + i1) * (SD * SD)))[e];
            }
        }
        // ---- stage w[cc..cc+CHUNK-1, :, all 81 taps] into LDS (contiguous slab) ----
        {
            const float4* src = (const float4*)(w + (size_t)cc * 32 * NTAP);
            float4*       dst = (float4*)wsl;
            for (int idx = t; idx < CHUNK * 32 * NTAP / 4; idx += THREADS)
                dst[idx] = src[idx];
        }
        __syncthreads();

        // ---- compute ----
        for (int ci = 0; ci < CHUNK; ++ci) {
            for (int s0 = 0; s0 < n0; ++s0) {
                for (int s1 = 0; s1 < n1; ++s1) {
                    const int k0 = k0lo + s0, k1 = k1lo + s1;
                    const float* wp0 = &wsl[(ci * 32 + co) * NTAP + (k0 * 3 + k1) * 9];
                    const float* wp1 = wp0 + 16 * NTAP;
                    float wv0[9], wv1[9];
#pragma unroll
                    for (int q = 0; q < 9; ++q) { wv0[q] = wp0[q]; wv1[q] = wp1[q]; }
                    const float* base = (const float*)xs4[ci][s0][s1];
#pragma unroll
                    for (int k2 = 0; k2 < 3; ++k2) {
                        const int i2 = o2 - k2;
                        if ((unsigned)i2 < (unsigned)SD) {
                            const float* xr = base + i2 * SD + i3b;
                            const float4 xa = ((const float4*)xr)[0];
                            const float4 xb = ((const float4*)xr)[1];
                            const float xv[8] = {xa.x, xa.y, xa.z, xa.w,
                                                 xb.x, xb.y, xb.z, xb.w};
#pragma unroll
                            for (int k3 = 0; k3 < 3; ++k3) {
                                const float c0 = wv0[k2 * 3 + k3];
                                const float c1 = wv1[k2 * 3 + k3];
#pragma unroll
                                for (int m = 0; m < 8; ++m) {
                                    a0[m + k3] += c0 * xv[m];   // o3 = 8h + m + k3
                                    a1[m + k3] += c1 * xv[m];
                                }
                            }
                        }
                    }
                }
            }
        }
        __syncthreads();
    }

    // ---- combine overlap (o3 = 8,9) via LDS, then write with bias ----
    float* bnd = (float*)xs4;            // xs dead after final barrier (2304 floats < 18.4KB)
    const int slot = (o2 * 16 + co) * 4;
    if (h == 0) {
        bnd[slot + 0] = a0[8]; bnd[slot + 1] = a0[9];
        bnd[slot + 2] = a1[8]; bnd[slot + 3] = a1[9];
    }
    __syncthreads();

    const float bb0 = bias[co], bb1 = bias[co + 16];
    float* y0 = y + (((((size_t)b * 32 + co) * OD + o0) * OD + o1) * OD + o2) * OD;
    float* y1 = y0 + (size_t)16 * OD * OD * OD * OD;
    if (h == 0) {
        // o3 = 0..7
#pragma unroll
        for (int j = 0; j < 4; ++j) {
            ((float2*)y0)[j] = make_float2(a0[2 * j] + bb0, a0[2 * j + 1] + bb0);
            ((float2*)y1)[j] = make_float2(a1[2 * j] + bb1, a1[2 * j + 1] + bb1);
        }
    } else {
        // o3 = 8..17 ; slots 0,1 get the h=0 partial for o3=8,9
        a0[0] += bnd[slot + 0]; a0[1] += bnd[slot + 1];
        a1[0] += bnd[slot + 2]; a1[1] += bnd[slot + 3];
#pragma unroll
        for (int j = 0; j < 5; ++j) {
            ((float2*)(y0 + 8))[j] = make_float2(a0[2 * j] + bb0, a0[2 * j + 1] + bb0);
            ((float2*)(y1 + 8))[j] = make_float2(a1[2 * j] + bb1, a1[2 * j + 1] + bb1);
        }
    }
}

extern "C" void kernel_launch(void* const* d_in, const int* in_sizes, int n_in,
                              void* d_out, int out_size, void* d_ws, size_t ws_size,
                              hipStream_t stream) {
    const float* x    = (const float*)d_in[0];
    const float* w    = (const float*)d_in[1];
    const float* bias = (const float*)d_in[2];
    float* y = (float*)d_out;

    const int grid = B_ * OD * OD;   // 648 blocks: (b, o0, o1) LPT-ordered
    convt4d_kernel<<<grid, THREADS, 0, stream>>>(x, w, bias, y);
}

// Round 10
// 112.719 us; speedup vs baseline: 11.9691x; 5.0675x over previous
//
#include <hip/hip_runtime.h>
#include <hip/hip_bf16.h>

// ConvTranspose4d: B=2, CIN=32, COUT=32, S=16^4, K=3^4, pad=0, stride=1
// y[b,co,o] = bias[co] + sum_{ci,k} x[b,ci,o-k] w[ci,co,k],  out spatial 18^4.
//
// R7/R9 (fp32 VALU): 564/571us, VALUBusy 53-57%, MfmaUtil 0 — mix+latency bound.
// R10: bf16 MFMA rewrite. Prepack x->x_t (pos-major, ci-contig bf16) and
// w->w_t (tap-major) into d_ws; main kernel = implicit GEMM per (b,o0,o1):
// 11 M-tiles of 32 output positions x 32 co, K=32 ci per tap, 64 avg taps.
// Zero-bordered LDS plane kills all k2/k3 OOB predication. Epilogue transposes
// D through LDS for coalesced stores.

#define B_    2
#define CIN_  32
#define SD    16
#define OD    18
#define NTAP  81
#define THREADS 256

typedef unsigned short u16;
typedef __attribute__((ext_vector_type(8))) short short8v;     // 8 bf16 = 4 VGPR
typedef __attribute__((ext_vector_type(8))) unsigned short u16x8;
typedef __attribute__((ext_vector_type(16))) float f32x16;     // 32x32 D frag

__device__ inline u16 f2bf(float f) {
    unsigned u = __float_as_uint(f);
    u = (u + 0x7FFFu + ((u >> 16) & 1u)) >> 16;   // RNE
    return (u16)u;
}

// LPT block ordering (kept from r7; proven bijective)
__device__ inline void decode_o01(int r, int& o0, int& o1) {
    if (r < 196) { o0 = 2 + r / 14; o1 = 2 + r % 14; }
    else if (r < 252) { int q = r - 196;
        if (q < 28) { o0 = 2 + (q >> 1); o1 = (q & 1) ? 16 : 1; }
        else { q -= 28; o1 = 2 + (q >> 1); o0 = (q & 1) ? 16 : 1; } }
    else if (r < 256) { int q = r - 252; o0 = (q & 1) ? 16 : 1; o1 = (q >> 1) ? 16 : 1; }
    else if (r < 312) { int q = r - 256;
        if (q < 28) { o0 = 2 + (q >> 1); o1 = (q & 1) ? 17 : 0; }
        else { q -= 28; o1 = 2 + (q >> 1); o0 = (q & 1) ? 17 : 0; } }
    else if (r < 320) { int q = r - 312;
        if (q < 4) { o0 = (q & 1) ? 16 : 1; o1 = (q >> 1) ? 17 : 0; }
        else { q -= 4; o0 = (q & 1) ? 17 : 0; o1 = (q >> 1) ? 16 : 1; } }
    else { int q = r - 320; o0 = (q & 1) ? 17 : 0; o1 = (q >> 1) ? 17 : 0; }
}

// ---------------- prepack: x_t (bf16, [b*256+plane][cg][pos][8ci]) + w_t ([tap][co][ci]) ----
__global__ __launch_bounds__(THREADS)
void prepack_kernel(const float* __restrict__ x, const float* __restrict__ w,
                    u16* __restrict__ xt, u16* __restrict__ wt) {
    const int bid = blockIdx.x, t = threadIdx.x;
    if (bid < 512) {
        const int b = bid >> 8, plane = bid & 255;
        const float* xp = x + (size_t)b * 32 * 65536 + plane * 256 + t;
#pragma unroll
        for (int cg = 0; cg < 4; ++cg) {
            u16x8 v;
#pragma unroll
            for (int j = 0; j < 8; ++j)
                v[j] = f2bf(xp[(size_t)(cg * 8 + j) * 65536]);
            *(u16x8*)(xt + ((size_t)(bid * 4 + cg) * 256 + t) * 8) = v;
        }
    } else {
        const int tap = bid - 512;                 // 0..80
#pragma unroll
        for (int q = 0; q < 4; ++q) {
            const int idx = t + q * 256;
            const int ci = idx >> 5, co = idx & 31;
            wt[tap * 1024 + co * 32 + ci] = f2bf(w[((size_t)ci * 32 + co) * NTAP + tap]);
        }
    }
}

// ---------------- main MFMA kernel ----------------
// LDS: x_plane [cg:4][20*20 pos'][8ci] bf16 = 25600 B (zero borders)
//      w_lds   [tap:9][g:4][co:32][8ci] bf16 = 18432 B at +25600
//      epilogue overlay: y_lds [p:324][33 words] f32 = 42768 B
__global__ __launch_bounds__(THREADS)
void convt4d_mfma(const u16* __restrict__ xt, const u16* __restrict__ wt,
                  const float* __restrict__ bias, float* __restrict__ y) {
    const int bid = blockIdx.x;
    const int b = bid & 1;
    int o0, o1; decode_o01(bid >> 1, o0, o1);
    const int t = threadIdx.x, l = t & 63, wv = t >> 6;
    const int hi = l >> 5, ln = l & 31;

    const int k0lo = max(0, o0 - (SD - 1)), k0hi = min(2, o0);
    const int k1lo = max(0, o1 - (SD - 1)), k1hi = min(2, o1);

    __shared__ __align__(16) char smem[44032];

    // zero x_plane region once; borders never rewritten
    for (int u = t; u < 1600; u += THREADS)
        *(float4*)(smem + u * 16) = make_float4(0.f, 0.f, 0.f, 0.f);

    // wave's 3 M-tiles (tile = 32 consecutive output positions p=o2*18+o3)
    int tiles[3] = { wv, wv + 4, (wv + 8) % 11 };   // covers 0..10; wv=3 dups tile 0 (benign)
    int lpos[3];
#pragma unroll
    for (int mi = 0; mi < 3; ++mi) {
        int p = 32 * tiles[mi] + ln; p = p > 323 ? 323 : p;   // clamp dead lanes in-bounds
        const int o2p = p / 18, o3p = p - o2p * 18;
        lpos[mi] = (o2p + 2) * 20 + o3p + 2;
    }

    f32x16 acc[3];
    { const float bb = bias[ln];                    // D col = lane&31 = co
#pragma unroll
      for (int mi = 0; mi < 3; ++mi)
#pragma unroll
        for (int r = 0; r < 16; ++r) acc[mi][r] = bb;
    }

    for (int k0 = k0lo; k0 <= k0hi; ++k0)
    for (int k1 = k1lo; k1 <= k1hi; ++k1) {
        __syncthreads();                            // prev-iter LDS reads done / zeros visible
        // stage x plane (i0,i1) = (o0-k0, o1-k1): 1024 x 16B, linear -> bordered
        {
            const int plane = (o0 - k0) * 16 + (o1 - k1);
            const u16* src = xt + (size_t)(b * 256 + plane) * 4 * 2048;
#pragma unroll
            for (int q = 0; q < 4; ++q) {
                const int idx = t + q * THREADS;
                const int cg = idx >> 8, pos = idx & 255;
                u16x8 v = *(const u16x8*)(src + (size_t)idx * 8);
                *(u16x8*)(smem + (cg * 400 + ((pos >> 4) + 2) * 20 + (pos & 15) + 2) * 16) = v;
            }
        }
        // stage 9-tap weight slab, rearranged [tap][g][co][8ci]
        {
            const u16* srcw = wt + (k0 * 3 + k1) * 9 * 1024;
            for (int idx = t; idx < 1152; idx += THREADS) {
                const int tt = idx >> 7, r = idx & 127, g = r >> 5, co = r & 31;
                u16x8 v = *(const u16x8*)(srcw + tt * 1024 + co * 32 + g * 8);
                *(u16x8*)(smem + 25600 + tt * 2048 + g * 512 + co * 16) = v;
            }
        }
        __syncthreads();

#pragma unroll
        for (int tt = 0; tt < 9; ++tt) {            // (k2,k3)
            const int sh = (tt / 3) * 20 + (tt % 3);
            const int wb = 25600 + tt * 2048 + hi * 512 + ln * 16;
            short8v b0 = *(const short8v*)(smem + wb);          // ci 0..15 half
            short8v b1 = *(const short8v*)(smem + wb + 1024);   // ci 16..31 half
#pragma unroll
            for (int mi = 0; mi < 3; ++mi) {
                const int ab = (hi * 400 + lpos[mi] - sh) * 16;
                short8v a0 = *(const short8v*)(smem + ab);           // cg 0/1
                short8v a1 = *(const short8v*)(smem + ab + 12800);   // cg 2/3
                acc[mi] = __builtin_amdgcn_mfma_f32_32x32x16_bf16(a0, b0, acc[mi], 0, 0, 0);
                acc[mi] = __builtin_amdgcn_mfma_f32_32x32x16_bf16(a1, b1, acc[mi], 0, 0, 0);
            }
        }
    }

    // ---- epilogue: D -> LDS transpose -> coalesced stores ----
    __syncthreads();
#pragma unroll
    for (int mi = 0; mi < 3; ++mi) {
        const int pb = 32 * tiles[mi] + 4 * hi;
#pragma unroll
        for (int r = 0; r < 16; ++r) {
            const int p = pb + (r & 3) + 8 * (r >> 2);   // verified D row map
            if (p < 324) *(float*)(smem + (p * 33 + ln) * 4) = acc[mi][r];
        }
    }
    __syncthreads();
    {
        const size_t ybase = (size_t)b * 32 * 104976 + (size_t)(o0 * 18 + o1) * 324;
        for (int co = 0; co < 32; ++co) {
            const float v0 = *(const float*)(smem + (t * 33 + co) * 4);
            y[ybase + (size_t)co * 104976 + t] = v0;
            if (t < 324 - 256) {
                const float v1 = *(const float*)(smem + ((t + 256) * 33 + co) * 4);
                y[ybase + (size_t)co * 104976 + t + 256] = v1;
            }
        }
    }
}

// ---------------- fallback (r9 fp32 kernel, proven 571us) ----------------
__global__ __launch_bounds__(576, 5)
void convt4d_fp32(const float* __restrict__ x, const float* __restrict__ w,
                  const float* __restrict__ bias, float* __restrict__ y) {
    const int bid = blockIdx.x;
    const int b = bid & 1;
    int o0, o1; decode_o01(bid >> 1, o0, o1);
    const int t = threadIdx.x;
    const int co = t & 15, rr_ = t >> 4, h = rr_ & 1, o2 = rr_ >> 1, i3b = h * 8;
    const int k0lo = max(0, o0 - (SD - 1)), k0hi = min(2, o0);
    const int k1lo = max(0, o1 - (SD - 1)), k1hi = min(2, o1);
    const int n0 = k0hi - k0lo + 1, n1 = k1hi - k1lo + 1;
    __shared__ float4 xs4[2][3][3][64];
    __shared__ float wsl[2 * 32 * NTAP];
    float a0[10], a1[10];
#pragma unroll
    for (int j = 0; j < 10; ++j) { a0[j] = 0.f; a1[j] = 0.f; }
    for (int cc = 0; cc < CIN_; cc += 2) {
        const int total4 = 2 * n0 * n1 * 64;
        for (int idx = t; idx < total4; idx += 576) {
            const int rw = idx >> 6, e = idx & 63;
            const int ci = rw / (n0 * n1), r2 = rw - ci * (n0 * n1);
            const int s0 = r2 / n1, s1 = r2 - s0 * n1;
            const int i0 = o0 - (k0lo + s0), i1 = o1 - (k1lo + s1);
            xs4[ci][s0][s1][e] = ((const float4*)(x +
                ((((size_t)b * CIN_ + (cc + ci)) * SD + i0) * SD + i1) * 256))[e];
        }
        const float4* src = (const float4*)(w + (size_t)cc * 32 * NTAP);
        for (int idx = t; idx < 2 * 32 * NTAP / 4; idx += 576)
            ((float4*)wsl)[idx] = src[idx];
        __syncthreads();
        for (int ci = 0; ci < 2; ++ci)
        for (int s0 = 0; s0 < n0; ++s0)
        for (int s1 = 0; s1 < n1; ++s1) {
            const int k0 = k0lo + s0, k1 = k1lo + s1;
            const float* wp0 = &wsl[(ci * 32 + co) * NTAP + (k0 * 3 + k1) * 9];
            const float* wp1 = wp0 + 16 * NTAP;
            float wv0[9], wv1[9];
#pragma unroll
            for (int q = 0; q < 9; ++q) { wv0[q] = wp0[q]; wv1[q] = wp1[q]; }
            const float* base = (const float*)xs4[ci][s0][s1];
#pragma unroll
            for (int k2 = 0; k2 < 3; ++k2) {
                const int i2 = o2 - k2;
                if ((unsigned)i2 < (unsigned)SD) {
                    const float* xr = base + i2 * SD + i3b;
                    const float4 xa = ((const float4*)xr)[0];
                    const float4 xb = ((const float4*)xr)[1];
                    const float xv[8] = {xa.x, xa.y, xa.z, xa.w, xb.x, xb.y, xb.z, xb.w};
#pragma unroll
                    for (int k3 = 0; k3 < 3; ++k3) {
                        const float c0 = wv0[k2 * 3 + k3], c1 = wv1[k2 * 3 + k3];
#pragma unroll
                        for (int m = 0; m < 8; ++m) {
                            a0[m + k3] += c0 * xv[m]; a1[m + k3] += c1 * xv[m];
                        }
                    }
                }
            }
        }
        __syncthreads();
    }
    float* bnd = (float*)xs4;
    const int slot = (o2 * 16 + co) * 4;
    if (h == 0) { bnd[slot] = a0[8]; bnd[slot + 1] = a0[9]; bnd[slot + 2] = a1[8]; bnd[slot + 3] = a1[9]; }
    __syncthreads();
    const float bb0 = bias[co], bb1 = bias[co + 16];
    float* y0 = y + (((((size_t)b * 32 + co) * OD + o0) * OD + o1) * OD + o2) * OD;
    float* y1 = y0 + (size_t)16 * OD * OD * OD * OD;
    if (h == 0) {
#pragma unroll
        for (int j = 0; j < 4; ++j) {
            ((float2*)y0)[j] = make_float2(a0[2 * j] + bb0, a0[2 * j + 1] + bb0);
            ((float2*)y1)[j] = make_float2(a1[2 * j] + bb1, a1[2 * j + 1] + bb1);
        }
    } else {
        a0[0] += bnd[slot]; a0[1] += bnd[slot + 1]; a1[0] += bnd[slot + 2]; a1[1] += bnd[slot + 3];
#pragma unroll
        for (int j = 0; j < 5; ++j) {
            ((float2*)(y0 + 8))[j] = make_float2(a0[2 * j] + bb0, a0[2 * j + 1] + bb0);
            ((float2*)(y1 + 8))[j] = make_float2(a1[2 * j] + bb1, a1[2 * j + 1] + bb1);
        }
    }
}

extern "C" void kernel_launch(void* const* d_in, const int* in_sizes, int n_in,
                              void* d_out, int out_size, void* d_ws, size_t ws_size,
                              hipStream_t stream) {
    const float* x    = (const float*)d_in[0];
    const float* w    = (const float*)d_in[1];
    const float* bias = (const float*)d_in[2];
    float* y = (float*)d_out;

    const size_t WT_BYTES = 262144;                 // w_t region (166KB used, aligned)
    const size_t XT_BYTES = (size_t)512 * 4 * 256 * 16;   // 8.39 MB
    if (ws_size >= WT_BYTES + XT_BYTES) {
        u16* wt = (u16*)d_ws;
        u16* xt = (u16*)((char*)d_ws + WT_BYTES);
        prepack_kernel<<<593, THREADS, 0, stream>>>(x, w, xt, wt);
        convt4d_mfma<<<B_ * OD * OD, THREADS, 0, stream>>>(xt, wt, bias, y);
    } else {
        convt4d_fp32<<<B_ * OD * OD, 576, 0, stream>>>(x, w, bias, y);
    }
}